// Round 2
// baseline (476.143 us; speedup 1.0000x reference)
//
#include <hip/hip_runtime.h>

// Haar inverse DWT2 (db1), fp32.
// Inputs: A, H, V, D each [8,32,256,256] fp32 (flat 16,777,216 elems).
// Output: [8,32,512,512] fp32 (flat 67,108,864 elems).
// x[2i,2j]   = (A+H+V+D)/2    x[2i,2j+1] = (A+H-V-D)/2
// x[2i+1,2j] = (A-H+V-D)/2    x[2i+1,2j+1] = (A-H-V+D)/2
//
// v2b: float4 loads (16 B/lane coalescing sweet spot, G13), one wave = one
// full input row -> two full 2 KB output rows; wave-uniform row/img index
// math; nontemporal stores (output is never re-read; in+out = 512 MB > L3).
// Use clang ext_vector_type(4) — __builtin_nontemporal_store rejects the
// HIP_vector_type float4 struct.

typedef float fvec4 __attribute__((ext_vector_type(4)));

#define IN_H 256
#define IN_W 256
#define N_IMG (8 * 32)
#define QUADS_PER_ROW (IN_W / 4)                    // 64 = one wave per row
#define TOTAL_QUADS (N_IMG * IN_H * QUADS_PER_ROW)  // 4,194,304

__global__ __launch_bounds__(256) void idwt2_haar_kernel(
    const float* __restrict__ A, const float* __restrict__ Hc,
    const float* __restrict__ V, const float* __restrict__ D,
    float* __restrict__ out) {
  int p = blockIdx.x * blockDim.x + threadIdx.x;  // global quad index
  if (p >= TOTAL_QUADS) return;

  // quad layout matches flat fvec4 layout of the inputs
  const fvec4 a = ((const fvec4*)A)[p];
  const fvec4 h = ((const fvec4*)Hc)[p];
  const fvec4 v = ((const fvec4*)V)[p];
  const fvec4 d = ((const fvec4*)D)[p];

  // pair 0 = input cols (4q, 4q+1); pair 1 = input cols (4q+2, 4q+3)
  float lp0 = a.x + h.x, lm0 = a.x - h.x;
  float mp0 = v.x + d.x, mm0 = v.x - d.x;
  float lp1 = a.y + h.y, lm1 = a.y - h.y;
  float mp1 = v.y + d.y, mm1 = v.y - d.y;
  float lp2 = a.z + h.z, lm2 = a.z - h.z;
  float mp2 = v.z + d.z, mm2 = v.z - d.z;
  float lp3 = a.w + h.w, lm3 = a.w - h.w;
  float mp3 = v.w + d.w, mm3 = v.w - d.w;

  fvec4 e0, e1, o0, o1;  // even row cols 8q..8q+7, odd row cols 8q..8q+7
  e0.x = 0.5f * (lp0 + mp0);
  e0.y = 0.5f * (lp0 - mp0);
  e0.z = 0.5f * (lp1 + mp1);
  e0.w = 0.5f * (lp1 - mp1);
  e1.x = 0.5f * (lp2 + mp2);
  e1.y = 0.5f * (lp2 - mp2);
  e1.z = 0.5f * (lp3 + mp3);
  e1.w = 0.5f * (lp3 - mp3);
  o0.x = 0.5f * (lm0 + mm0);
  o0.y = 0.5f * (lm0 - mm0);
  o0.z = 0.5f * (lm1 + mm1);
  o0.w = 0.5f * (lm1 - mm1);
  o1.x = 0.5f * (lm2 + mm2);
  o1.y = 0.5f * (lm2 - mm2);
  o1.z = 0.5f * (lm3 + mm3);
  o1.w = 0.5f * (lm3 - mm3);

  int q = p & (QUADS_PER_ROW - 1);  // 0..63  == lane (wave-aligned)
  int i = (p >> 6) & (IN_H - 1);    // wave-uniform input row
  int img = p >> 14;                // wave-uniform image

  size_t obase =
      ((size_t)img * (2 * IN_H) + 2 * (size_t)i) * (2 * IN_W) + 8 * (size_t)q;
  __builtin_nontemporal_store(e0, (fvec4*)(out + obase));
  __builtin_nontemporal_store(e1, (fvec4*)(out + obase + 4));
  __builtin_nontemporal_store(o0, (fvec4*)(out + obase + 2 * IN_W));
  __builtin_nontemporal_store(o1, (fvec4*)(out + obase + 2 * IN_W + 4));
}

extern "C" void kernel_launch(void* const* d_in, const int* in_sizes, int n_in,
                              void* d_out, int out_size, void* d_ws,
                              size_t ws_size, hipStream_t stream) {
  const float* A = (const float*)d_in[0];
  const float* Hc = (const float*)d_in[1];
  const float* V = (const float*)d_in[2];
  const float* D = (const float*)d_in[3];
  float* out = (float*)d_out;

  const int threads = 256;
  const int blocks = TOTAL_QUADS / threads;  // 16384
  idwt2_haar_kernel<<<blocks, threads, 0, stream>>>(A, Hc, V, D, out);
}

// Round 3
// 430.901 us; speedup vs baseline: 1.1050x; 1.1050x over previous
//
#include <hip/hip_runtime.h>

// Haar inverse DWT2 (db1), fp32.
// Inputs: A, H, V, D each [8,32,256,256] fp32 (flat 16,777,216 elems).
// Output: [8,32,512,512] fp32 (flat 67,108,864 elems).
// x[2i,2j]   = (A+H+V+D)/2    x[2i,2j+1] = (A+H-V-D)/2
// x[2i+1,2j] = (A-H+V-D)/2    x[2i+1,2j+1] = (A-H-V+D)/2
//
// v3: revert to the coalescing-optimal v1 structure. Evidence from v2:
//  - strided 16B-at-32B-stride stores + nontemporal => WRITE_SIZE inflated
//    25% (320 MB vs 256 MB ideal) from partial-cacheline HBM writes; BW
//    dropped to 1.75 TB/s.
//  - float2 loads are already fully coalesced (512 B/wave/instr); VMEM
//    issue rate is not the limiter at 10 B/cyc/CU HBM-bound.
//  - per-lane float4 stores with consecutive lanes adjacent => each wave
//    store is 1024 B contiguous, every 64 B line written whole by one
//    instruction. No NT: zero reuse anywhere, nothing to protect, and
//    plain stores let L2 write-combine normally (fills hit 6.5 TB/s).

#define IN_H 256
#define IN_W 256
#define N_IMG (8 * 32)
#define PAIRS_PER_ROW (IN_W / 2)              // 128 = 2^7
#define PAIRS_PER_IMG (IN_H * PAIRS_PER_ROW)  // 32768 = 2^15
#define TOTAL_PAIRS (N_IMG * PAIRS_PER_IMG)   // 8,388,608

__global__ __launch_bounds__(256) void idwt2_haar_kernel(
    const float* __restrict__ A, const float* __restrict__ Hc,
    const float* __restrict__ V, const float* __restrict__ D,
    float* __restrict__ out) {
  int p = blockIdx.x * blockDim.x + threadIdx.x;  // global pair index
  if (p >= TOTAL_PAIRS) return;

  // pair layout matches flat float2 layout of the inputs
  const float2 a = ((const float2*)A)[p];
  const float2 h = ((const float2*)Hc)[p];
  const float2 v = ((const float2*)V)[p];
  const float2 d = ((const float2*)D)[p];

  // element 0 (input col 2j)
  float lp0 = a.x + h.x, lm0 = a.x - h.x;
  float mp0 = v.x + d.x, mm0 = v.x - d.x;
  // element 1 (input col 2j+1)
  float lp1 = a.y + h.y, lm1 = a.y - h.y;
  float mp1 = v.y + d.y, mm1 = v.y - d.y;

  float4 row_even, row_odd;
  row_even.x = 0.5f * (lp0 + mp0);
  row_even.y = 0.5f * (lp0 - mp0);
  row_even.z = 0.5f * (lp1 + mp1);
  row_even.w = 0.5f * (lp1 - mp1);
  row_odd.x = 0.5f * (lm0 + mm0);
  row_odd.y = 0.5f * (lm0 - mm0);
  row_odd.z = 0.5f * (lm1 + mm1);
  row_odd.w = 0.5f * (lm1 - mm1);

  int j = p & (PAIRS_PER_ROW - 1);        // 0..127 (lane-consecutive)
  int i = (p >> 7) & (IN_H - 1);          // 0..255 (wave-uniform)
  int img = p >> 15;                      // wave-uniform

  size_t obase =
      ((size_t)img * (2 * IN_H) + 2 * (size_t)i) * (2 * IN_W) + 4 * (size_t)j;
  // wave store = 64 lanes x 16 B at 16 B stride = 1024 B contiguous
  *(float4*)(out + obase) = row_even;             // row 2i, cols 4j..4j+3
  *(float4*)(out + obase + 2 * IN_W) = row_odd;   // row 2i+1
}

extern "C" void kernel_launch(void* const* d_in, const int* in_sizes, int n_in,
                              void* d_out, int out_size, void* d_ws,
                              size_t ws_size, hipStream_t stream) {
  const float* A = (const float*)d_in[0];
  const float* Hc = (const float*)d_in[1];
  const float* V = (const float*)d_in[2];
  const float* D = (const float*)d_in[3];
  float* out = (float*)d_out;

  const int threads = 256;
  const int blocks = TOTAL_PAIRS / threads;  // 32768
  idwt2_haar_kernel<<<blocks, threads, 0, stream>>>(A, Hc, V, D, out);
}